// Round 5
// baseline (1067.036 us; speedup 1.0000x reference)
//
#include <hip/hip_runtime.h>

#define NNODES 100000
#define NEDGES 3200000
#define NFEAT  512
#define NHID   16
#define NCLS   64
#define NB     391      // ceil(100000/256) buckets of 256 nodes (bucket = dst>>8)
#define CAP    10240    // per-bucket edge capacity (mean 8192, sd ~90)
#define EPB    8192     // edges per block in pass A

typedef short bf16x8 __attribute__((ext_vector_type(8)));
typedef float f32x4  __attribute__((ext_vector_type(4)));

__device__ __forceinline__ short f2bf(float f) {
    unsigned u = __float_as_uint(f);
    return (short)((u + 0x7FFFu + ((u >> 16) & 1u)) >> 16);
}

// ---- pass A: partition edges into 391 coarse buckets, LDS-staged coalesced writes
// packed entry: src (17 bits) | dstLow (8 bits) << 17
__global__ __launch_bounds__(256) void k_part(const int* __restrict__ src,
                                              const int* __restrict__ dst,
                                              unsigned* __restrict__ gcnt,
                                              unsigned* __restrict__ part) {
    __shared__ unsigned hist[NB];
    __shared__ unsigned scn[512];
    __shared__ unsigned cursor[NB];
    __shared__ unsigned delta[NB];
    __shared__ unsigned staged[EPB];
    __shared__ unsigned short pbkt[EPB];
    int t = threadIdx.x;
    int base = blockIdx.x * EPB;
    int nblk = min(EPB, NEDGES - base);
    for (int i = t; i < NB; i += 256) hist[i] = 0;
    __syncthreads();
    unsigned pk[32]; unsigned short bk[32];
#pragma unroll
    for (int j = 0; j < 32; ++j) {
        int o = t + j * 256;
        if (o < nblk) {
            int s = src[base + o], d = dst[base + o];
            pk[j] = (unsigned)s | ((unsigned)(d & 255) << 17);
            bk[j] = (unsigned short)(d >> 8);
            atomicAdd(&hist[bk[j]], 1u);
        } else bk[j] = 0xFFFFu;
    }
    __syncthreads();
    scn[t] = (t < NB) ? hist[t] : 0u;
    scn[t + 256] = (t + 256 < NB) ? hist[t + 256] : 0u;
    __syncthreads();
#pragma unroll
    for (int off = 1; off < 512; off <<= 1) {
        unsigned a = (t >= off) ? scn[t - off] : 0u;
        unsigned b = (t + 256 >= off) ? scn[t + 256 - off] : 0u;
        __syncthreads();
        scn[t] += a; scn[t + 256] += b;
        __syncthreads();
    }
    for (int i = t; i < NB; i += 256) {
        unsigned h = hist[i];
        unsigned ex = scn[i] - h;
        cursor[i] = ex;
        unsigned gb = h ? atomicAdd(&gcnt[i], h) : 0u;
        delta[i] = (unsigned)i * CAP + gb - ex;
    }
    __syncthreads();
#pragma unroll
    for (int j = 0; j < 32; ++j) {
        if (bk[j] != 0xFFFFu) {
            unsigned p = atomicAdd(&cursor[bk[j]], 1u);
            staged[p] = pk[j];
            pbkt[p] = bk[j];
        }
    }
    __syncthreads();
    for (int i = t; i < nblk; i += 256) {
        unsigned b = pbkt[i];
        unsigned d = delta[b] + (unsigned)i;
        if (d < (b + 1u) * CAP) part[d] = staged[i];
    }
}

// ---- per-bucket degree histogram -> dinv only (CSR eliminated)
__global__ __launch_bounds__(256) void k_deg2(const unsigned* __restrict__ gcnt,
                                              const unsigned* __restrict__ part,
                                              float* __restrict__ dinv) {
    __shared__ unsigned hist[256];
    int t = threadIdx.x, b = blockIdx.x;
    hist[t] = 0;
    __syncthreads();
    unsigned n = gcnt[b]; if (n > CAP) n = CAP;
    const unsigned* seg = part + (size_t)b * CAP;
    for (unsigned i = t; i < n; i += 256)
        atomicAdd(&hist[(seg[i] >> 17) & 255u], 1u);
    __syncthreads();
    int node = b * 256 + t;
    if (node < NNODES) dinv[node] = rsqrtf((float)hist[t] + 1.f);  // +1 self-loop
}

// ---- hs1 = (x @ W1) * dinv[row]  (bf16 MFMA inside)
__global__ __launch_bounds__(256) void k_gemm1(const float* __restrict__ x,
                                               const float* __restrict__ w1,
                                               const float* __restrict__ dinv,
                                               float* __restrict__ hs1) {
    __shared__ short w1t[16][520];
    int tid = threadIdx.x;
    for (int idx = tid; idx < NFEAT * NHID; idx += 256) {
        int k = idx >> 4, n = idx & 15;
        w1t[n][k] = f2bf(w1[idx]);
    }
    __syncthreads();
    int wave = tid >> 6, lane = tid & 63;
    int tile = blockIdx.x * 4 + wave;
    if (tile >= NNODES / 16) return;
    int m = lane & 15, q = lane >> 4;
    const float* xrow = x + (size_t)(tile * 16 + m) * NFEAT + q * 8;
    const short* wrow = &w1t[m][q * 8];
    f32x4 acc = {0.f, 0.f, 0.f, 0.f};
#pragma unroll
    for (int kb = 0; kb < NFEAT / 32; ++kb) {
        float4 a0 = *(const float4*)(xrow + kb * 32);
        float4 a1 = *(const float4*)(xrow + kb * 32 + 4);
        bf16x8 a;
        a[0] = f2bf(a0.x); a[1] = f2bf(a0.y); a[2] = f2bf(a0.z); a[3] = f2bf(a0.w);
        a[4] = f2bf(a1.x); a[5] = f2bf(a1.y); a[6] = f2bf(a1.z); a[7] = f2bf(a1.w);
        bf16x8 b = *(const bf16x8*)(wrow + kb * 32);
        acc = __builtin_amdgcn_mfma_f32_16x16x32_bf16(a, b, acc, 0, 0, 0);
    }
    float* out = hs1 + (size_t)(tile * 16) * NHID;
#pragma unroll
    for (int r = 0; r < 4; ++r) {
        int row = q * 4 + r;
        out[row * NHID + m] = acc[r] * dinv[tile * 16 + row];
    }
}

// ---- layer-1: per-bucket gather + LDS scatter-add + self-loop + bias + relu
__global__ __launch_bounds__(1024) void k_agg1(const unsigned* __restrict__ gcnt,
                                               const unsigned* __restrict__ part,
                                               const float* __restrict__ hs1,
                                               const float* __restrict__ dinv,
                                               const float* __restrict__ b1,
                                               float* __restrict__ hs2) {
    __shared__ float acc[256 * 17];   // stride 17 breaks bank aliasing
    int t = threadIdx.x, b = blockIdx.x;
    for (int i = t; i < 256 * 17; i += 1024) acc[i] = 0.f;
    __syncthreads();
    unsigned n = gcnt[b]; if (n > CAP) n = CAP;
    const unsigned* seg = part + (size_t)b * CAP;
    int q = t & 3, sl = t >> 2;       // 4 lanes/edge, 256 edges in flight/block
    for (unsigned j = sl; j < n; j += 256) {
        unsigned p = seg[j];
        float4 v = *(const float4*)(hs1 + (size_t)(p & 0x1FFFFu) * NHID + q * 4);
        float* a = &acc[((p >> 17) & 255u) * 17 + q * 4];
        atomicAdd(a + 0, v.x); atomicAdd(a + 1, v.y);
        atomicAdd(a + 2, v.z); atomicAdd(a + 3, v.w);
    }
    __syncthreads();
    int base = b * 256;
    for (int i = t; i < 4096; i += 1024) {
        int n0 = i >> 4, ff = i & 15;
        int node = base + n0;
        if (node < NNODES) {
            float di = dinv[node];
            float v = (acc[n0 * 17 + ff] + hs1[(size_t)node * NHID + ff]) * di + b1[ff];
            v = v > 0.f ? v : 0.f;
            hs2[(size_t)node * NHID + ff] = v * di;   // pre-scale for layer 2
        }
    }
}

// ---- layer-2: gather + LDS scatter-add + self-loop + W2 matvec + b2 + log_softmax
__global__ __launch_bounds__(1024) void k_out2(const unsigned* __restrict__ gcnt,
                                               const unsigned* __restrict__ part,
                                               const float* __restrict__ hs2,
                                               const float* __restrict__ dinv,
                                               const float* __restrict__ w2,
                                               const float* __restrict__ b2,
                                               float* __restrict__ out) {
    __shared__ float acc[256 * 17];
    __shared__ float w2f[NHID * NCLS];   // 1024 floats exactly
    __shared__ float b2f[NCLS];
    int t = threadIdx.x, b = blockIdx.x;
    for (int i = t; i < 256 * 17; i += 1024) acc[i] = 0.f;
    w2f[t] = w2[t];
    if (t < NCLS) b2f[t] = b2[t];
    __syncthreads();
    unsigned n = gcnt[b]; if (n > CAP) n = CAP;
    const unsigned* seg = part + (size_t)b * CAP;
    int q = t & 3, sl = t >> 2;
    for (unsigned j = sl; j < n; j += 256) {
        unsigned p = seg[j];
        float4 v = *(const float4*)(hs2 + (size_t)(p & 0x1FFFFu) * NHID + q * 4);
        float* a = &acc[((p >> 17) & 255u) * 17 + q * 4];
        atomicAdd(a + 0, v.x); atomicAdd(a + 1, v.y);
        atomicAdd(a + 2, v.z); atomicAdd(a + 3, v.w);
    }
    __syncthreads();
    int c = t & 63, g = t >> 6;          // wave g handles nodes g, g+16, ...
    for (int n0 = g; n0 < 256; n0 += 16) {
        int node = b * 256 + n0;
        if (node >= NNODES) break;       // wave-uniform
        float di = dinv[node];
        float logit = b2f[c];
#pragma unroll
        for (int k = 0; k < NHID; ++k) {
            float v = (acc[n0 * 17 + k] + hs2[(size_t)node * NHID + k]) * di;
            logit += v * w2f[k * NCLS + c];
        }
        float mx = logit;
#pragma unroll
        for (int off = 32; off > 0; off >>= 1) mx = fmaxf(mx, __shfl_xor(mx, off));
        float ex = __expf(logit - mx);
        float s = ex;
#pragma unroll
        for (int off = 32; off > 0; off >>= 1) s += __shfl_xor(s, off);
        out[(size_t)node * NCLS + c] = logit - mx - logf(s);
    }
}

extern "C" void kernel_launch(void* const* d_in, const int* in_sizes, int n_in,
                              void* d_out, int out_size, void* d_ws, size_t ws_size,
                              hipStream_t stream) {
    const float* x  = (const float*)d_in[0];   // f32 [100000,512]
    const int*   ei = (const int*)d_in[1];     // int32 [2,3200000]
    const float* w1 = (const float*)d_in[2];   // f32 [512,16]
    const float* b1 = (const float*)d_in[3];   // f32 [16]
    const float* w2 = (const float*)d_in[4];   // f32 [16,64]
    const float* b2 = (const float*)d_in[5];   // f32 [64]
    const int* src = ei;
    const int* dst = ei + NEDGES;

    char* ws = (char*)d_ws;
    unsigned* gcnt = (unsigned*)(ws + 0);          //     2,048 B
    float*    dinv = (float*)   (ws + 2048);       //   400,000 B
    float*    hs1  = (float*)   (ws + 402048);     // 6,400,000 B
    float*    hs2  = (float*)   (ws + 6802048);    // 6,400,000 B
    unsigned* part = (unsigned*)(ws + 13202048);   // 16,015,360 B (total ~29.2 MB)

    hipMemsetAsync(gcnt, 0, 2048, stream);
    k_part <<<NB, 256, 0, stream>>>(src, dst, gcnt, part);
    k_deg2 <<<NB, 256, 0, stream>>>(gcnt, part, dinv);
    k_gemm1<<<(NNODES / 16 + 3) / 4, 256, 0, stream>>>(x, w1, dinv, hs1);
    k_agg1 <<<NB, 1024, 0, stream>>>(gcnt, part, hs1, dinv, b1, hs2);
    k_out2 <<<NB, 1024, 0, stream>>>(gcnt, part, hs2, dinv, w2, b2, (float*)d_out);
}